// Round 4
// baseline (955.989 us; speedup 1.0000x reference)
//
#include <hip/hip_runtime.h>

#define NB 32
#define NS 512
#define NE 128
#define NU 10000
#define WROWS 1152

typedef __attribute__((ext_vector_type(8))) short bf16x8;
typedef __attribute__((ext_vector_type(4))) float f32x4;

__device__ __forceinline__ unsigned short f2bf(float f) {
    unsigned int u = __float_as_uint(f);
    u += 0x7fff + ((u >> 16) & 1);   // round-to-nearest-even
    return (unsigned short)(u >> 16);
}

// Kernel 1: last-previous-occurrence tables for users and items.
__global__ void prev_kernel(const int* __restrict__ users, const int* __restrict__ items,
                            int* __restrict__ prevU, int* __restrict__ prevI) {
    const int b = blockIdx.x;
    const int which = blockIdx.y;
    const int t = threadIdx.x;
    const int* arr = (which ? items : users) + b * NS;
    __shared__ int sh[NS];
    sh[t] = arr[t];
    __syncthreads();
    const int idx = sh[t];
    int p = -1;
    for (int u = t - 1; u >= 0; --u) {
        if (sh[u] == idx) { p = u; break; }
    }
    (which ? prevI : prevU)[b * NS + t] = p;
}

// Kernel 2: one block per batch chain. 8 waves; W_stack (1152x128) lives in
// registers as bf16 MFMA A-fragments (wave w owns rows [w*144, w*144+144)).
// Per step: y = W @ [ue, ie] via 36 MFMAs/wave -> LDS -> gate phase (256
// threads) -> stage next x (prefetched one step ahead).
__global__ __launch_bounds__(512, 2) void limnet_main(
    const int* __restrict__ users, const int* __restrict__ items,
    const float* __restrict__ umem0, const float* __restrict__ imem0,
    const float* __restrict__ w_ih, const float* __restrict__ w_hh,
    const float* __restrict__ b_ih, const float* __restrict__ b_hh,
    const int* __restrict__ prevU, const int* __restrict__ prevI,
    float* uout, float* iout)
{
    const int b = blockIdx.x;
    const int tid = threadIdx.x;
    const int lane = tid & 63;
    const int wave = tid >> 6;
    const int col = lane & 15;      // MFMA A row-in-tile / B-&-D column
    const int kgrp = lane >> 4;     // 0..3: which 8-wide k slice

    __shared__ __align__(16) float y[2][WROWS];          // y[col][row]
    __shared__ __align__(16) float xf[2][NE];            // f32 x (h_old)
    __shared__ __align__(16) unsigned short xb[2][NE];   // bf16 x for MFMA

    // ---- one-time: load W_stack into registers as bf16 fragments ----
    // W_stack row R: R<384 -> w_ih[R, 0:128]; R<768 -> w_ih[R-384, 128:256];
    // else w_hh[R-768, :]. A-frag: lane holds A[row=col][k=kt*32+kgrp*8+j].
    bf16x8 wfrag[9][4];
#pragma unroll
    for (int m9 = 0; m9 < 9; ++m9) {
        const int row = wave * 144 + m9 * 16 + col;
#pragma unroll
        for (int kt = 0; kt < 4; ++kt) {
            const int k = kt * 32 + kgrp * 8;
            const float* src;
            if (row < 384)      src = w_ih + (size_t)row * 256 + k;
            else if (row < 768) src = w_ih + (size_t)(row - 384) * 256 + 128 + k;
            else                src = w_hh + (size_t)(row - 768) * 128 + k;
            const float4 f0 = *(const float4*)(src);
            const float4 f1 = *(const float4*)(src + 4);
            bf16x8 wv;
            wv[0] = (short)f2bf(f0.x); wv[1] = (short)f2bf(f0.y);
            wv[2] = (short)f2bf(f0.z); wv[3] = (short)f2bf(f0.w);
            wv[4] = (short)f2bf(f1.x); wv[5] = (short)f2bf(f1.y);
            wv[6] = (short)f2bf(f1.z); wv[7] = (short)f2bf(f1.w);
            wfrag[m9][kt] = wv;
        }
    }

    // gate-thread constants (threads 0..255: gc=cell (0=user,1=item), ge=elem)
    const int gc = (tid >> 7) & 1;
    const int ge = tid & 127;
    // hoisted per-thread pointers for the gate/stage role
    const int*   g_idx  = (gc ? items : users) + b * NS;
    const int*   g_prev = (gc ? prevI : prevU) + b * NS;
    const float* g_mem0 = (gc ? imem0 : umem0) + (size_t)b * NU * NE + ge;
    float*       g_out  = (gc ? iout : uout) + (size_t)b * NS * NE + ge;

    float bir = 0.f, biz = 0.f, bin = 0.f, bhr = 0.f, bhz = 0.f, bhn = 0.f;
    if (tid < 256) {
        bir = b_ih[ge]; biz = b_ih[128 + ge]; bin = b_ih[256 + ge];
        bhr = b_hh[ge]; bhz = b_hh[128 + ge]; bhn = b_hh[256 + ge];
    }

    // ---- initial x staging (t = 0): always from mem0 (prev == -1) ----
    if (tid < 256) {
        const float v = g_mem0[(size_t)g_idx[0] * NE];
        xf[gc][ge] = v;
        xb[gc][ge] = f2bf(v);
    }
    __syncthreads();

    for (int t = 0; t < NS; ++t) {
        // ---- phase A: prefetch x_{t+1}; L2-warm the t+8 mem0 gather ----
        float vnext = 0.f;
        int pnext = -2;
        if (tid < 256 && t + 1 < NS) {
            const int nidx = g_idx[t + 1];
            const int p = g_prev[t + 1];
            pnext = p;
            if (p != t) {   // p == t: value produced this step, take from reg in E
                if (p < 0) vnext = g_mem0[(size_t)nidx * NE];
                else       vnext = g_out[(size_t)p * NE];
            }
        }
        if (tid < 256 && t + 8 < NS) {
            const int p8 = g_prev[t + 8];
            if (p8 < 0) {
                const float wv = g_mem0[(size_t)g_idx[t + 8] * NE];
                asm volatile("" :: "v"(wv));   // keep the warming load alive
            }
        }

        // ---- phase B/C: y = W_stack @ [ue, ie] via MFMA; write y to LDS ----
        bf16x8 bfrag[4];
#pragma unroll
        for (int kt = 0; kt < 4; ++kt) {
            if (col < 2) {
                bfrag[kt] = *(const bf16x8*)&xb[col][kt * 32 + kgrp * 8];
            } else {
                bf16x8 zz;
#pragma unroll
                for (int j = 0; j < 8; ++j) zz[j] = 0;
                bfrag[kt] = zz;
            }
        }
#pragma unroll
        for (int m9 = 0; m9 < 9; ++m9) {
            f32x4 a = {0.f, 0.f, 0.f, 0.f};
#pragma unroll
            for (int kt = 0; kt < 4; ++kt)
                a = __builtin_amdgcn_mfma_f32_16x16x32_bf16(wfrag[m9][kt], bfrag[kt], a, 0, 0, 0);
            if (col < 2) {   // D layout: col = lane&15, row = (lane>>4)*4 + reg
                const int row = wave * 144 + m9 * 16 + kgrp * 4;
                *(f32x4*)&y[col][row] = a;
            }
        }
        __syncthreads();

        // ---- phase D: gates + output write; phase E: stage next x ----
        if (tid < 256) {
            const int c1 = 1 - gc;
            // gi = A@x_self + B@x_other + b_ih ; gh = C@x_self + b_hh
            const float gir = y[gc][ge]        + y[c1][384 + ge] + bir;
            const float giz = y[gc][128 + ge]  + y[c1][512 + ge] + biz;
            const float gin = y[gc][256 + ge]  + y[c1][640 + ge] + bin;
            const float ghr = y[gc][768 + ge]  + bhr;
            const float ghz = y[gc][896 + ge]  + bhz;
            const float ghn = y[gc][1024 + ge] + bhn;
            const float r = 1.f / (1.f + __expf(-(gir + ghr)));
            const float z = 1.f / (1.f + __expf(-(giz + ghz)));
            const float pre = gin + r * ghn;
            const float n = 2.f / (1.f + __expf(-2.f * pre)) - 1.f;   // tanh, NaN-safe
            const float hold = xf[gc][ge];
            const float h = (1.f - z) * n + z * hold;
            g_out[(size_t)t * NE] = h;
            if (t + 1 < NS) {
                const float nx = (pnext == t) ? h : vnext;
                xf[gc][ge] = nx;
                xb[gc][ge] = f2bf(nx);
            }
        }
        __syncthreads();
    }
}

extern "C" void kernel_launch(void* const* d_in, const int* in_sizes, int n_in,
                              void* d_out, int out_size, void* d_ws, size_t ws_size,
                              hipStream_t stream) {
    const int*   users = (const int*)d_in[0];
    const int*   items = (const int*)d_in[1];
    const float* umem0 = (const float*)d_in[2];
    const float* imem0 = (const float*)d_in[3];
    const float* w_ih  = (const float*)d_in[4];
    const float* w_hh  = (const float*)d_in[5];
    const float* b_ih  = (const float*)d_in[6];
    const float* b_hh  = (const float*)d_in[7];

    float* uout = (float*)d_out;
    float* iout = uout + (size_t)NB * NS * NE;

    int* prevU = (int*)d_ws;
    int* prevI = prevU + NB * NS;

    prev_kernel<<<dim3(NB, 2), dim3(NS), 0, stream>>>(users, items, prevU, prevI);
    limnet_main<<<dim3(NB), dim3(512), 0, stream>>>(
        users, items, umem0, imem0, w_ih, w_hh, b_ih, b_hh, prevU, prevI, uout, iout);
}

// Round 6
// 782.973 us; speedup vs baseline: 1.2210x; 1.2210x over previous
//
#include <hip/hip_runtime.h>

#define NB 32
#define NS 512
#define NE 128
#define NU 10000

typedef __attribute__((ext_vector_type(8))) short bf16x8;
typedef __attribute__((ext_vector_type(4))) float f32x4;

__device__ __forceinline__ unsigned short f2bf(float f) {
    unsigned int u = __float_as_uint(f);
    u += 0x7fff + ((u >> 16) & 1);   // round-to-nearest-even
    return (unsigned short)(u >> 16);
}

// LDS-only barrier: drain LDS ops (cross-wave write->read ordering), leave
// global loads/stores in flight across the barrier (no vmcnt drain).
// sched_barrier(0) stops the compiler from hoisting LDS reads above s_barrier.
#define BARRIER() do { \
    asm volatile("s_waitcnt lgkmcnt(0)" ::: "memory"); \
    __builtin_amdgcn_s_barrier(); \
    __builtin_amdgcn_sched_barrier(0); \
} while (0)

// Kernel 1: last-previous-occurrence tables for users and items.
__global__ void prev_kernel(const int* __restrict__ users, const int* __restrict__ items,
                            int* __restrict__ prevU, int* __restrict__ prevI) {
    const int b = blockIdx.x;
    const int which = blockIdx.y;
    const int t = threadIdx.x;
    const int* arr = (which ? items : users) + b * NS;
    __shared__ int sh[NS];
    sh[t] = arr[t];
    __syncthreads();
    const int idx = sh[t];
    int p = -1;
    for (int u = t - 1; u >= 0; --u) {
        if (sh[u] == idx) { p = u; break; }
    }
    (which ? prevI : prevU)[b * NS + t] = p;
}

// Kernel 2: one block per batch chain. 8 waves; W_stack (1152x128) in
// registers as bf16 MFMA A-fragments. Per step:
//  region-1: issue async gathers for x_{t+1};
//            y = W @ [ue, ie] via 36 MFMAs/wave (kt-outer, 9 live accs)
//  BARRIER (LDS-only drain)
//  region-2: gates on threads 0..255; h -> global out (undrained) + LDS
//            h_hist window; stage x_{t+1} into xb (bf16)
//  BARRIER
__global__ __launch_bounds__(512, 1) void limnet_main(
    const int* __restrict__ users, const int* __restrict__ items,
    const float* __restrict__ umem0, const float* __restrict__ imem0,
    const float* __restrict__ w_ih, const float* __restrict__ w_hh,
    const float* __restrict__ b_ih, const float* __restrict__ b_hh,
    const int* __restrict__ prevU, const int* __restrict__ prevI,
    float* uout, float* iout)
{
    const int b = blockIdx.x;
    const int tid = threadIdx.x;
    const int lane = tid & 63;
    const int wave = tid >> 6;
    const int col = lane & 15;      // MFMA A row-in-tile / B-&-D column
    const int kgrp = lane >> 4;     // 0..3: which 8-wide k slice

    __shared__ __align__(16) float y[2][1152];           // y[col][row]
    __shared__ __align__(16) unsigned short xb[2][NE];   // bf16 x for MFMA
    __shared__ __align__(16) float hh[2][8][NE];         // h history window
    __shared__ int s_idx[2][NS];
    __shared__ int s_prev[2][NS];

    // ---- stage idx/prev tables into LDS (one-time) ----
    for (int i = tid; i < NS; i += 512) {
        s_idx[0][i]  = users[b * NS + i];
        s_idx[1][i]  = items[b * NS + i];
        s_prev[0][i] = prevU[b * NS + i];
        s_prev[1][i] = prevI[b * NS + i];
    }

    // ---- one-time: load W_stack into registers as bf16 fragments ----
    // W_stack row R: R<384 -> w_ih[R, 0:128]; R<768 -> w_ih[R-384, 128:256];
    // else w_hh[R-768, :]. A-frag: lane holds A[row=col][k=kt*32+kgrp*8+j].
    bf16x8 wfrag[9][4];
#pragma unroll
    for (int m9 = 0; m9 < 9; ++m9) {
        const int row = wave * 144 + m9 * 16 + col;
#pragma unroll
        for (int kt = 0; kt < 4; ++kt) {
            const int k = kt * 32 + kgrp * 8;
            const float* src;
            if (row < 384)      src = w_ih + (size_t)row * 256 + k;
            else if (row < 768) src = w_ih + (size_t)(row - 384) * 256 + 128 + k;
            else                src = w_hh + (size_t)(row - 768) * 128 + k;
            const float4 f0 = *(const float4*)(src);
            const float4 f1 = *(const float4*)(src + 4);
            bf16x8 wv;
            wv[0] = (short)f2bf(f0.x); wv[1] = (short)f2bf(f0.y);
            wv[2] = (short)f2bf(f0.z); wv[3] = (short)f2bf(f0.w);
            wv[4] = (short)f2bf(f1.x); wv[5] = (short)f2bf(f1.y);
            wv[6] = (short)f2bf(f1.z); wv[7] = (short)f2bf(f1.w);
            wfrag[m9][kt] = wv;
        }
    }

    // gate-thread constants (threads 0..255: gc=cell (0=user,1=item), ge=elem)
    const int gc = (tid >> 7) & 1;
    const int ge = tid & 127;
    const float* g_mem0 = (gc ? imem0 : umem0) + (size_t)b * NU * NE + ge;
    float*       g_out  = (gc ? iout : uout) + (size_t)b * NS * NE + ge;

    float bir = 0.f, biz = 0.f, bin = 0.f, bhr = 0.f, bhz = 0.f, bhn = 0.f;
    if (tid < 256) {
        bir = b_ih[ge]; biz = b_ih[128 + ge]; bin = b_ih[256 + ge];
        bhr = b_hh[ge]; bhz = b_hh[128 + ge]; bhn = b_hh[256 + ge];
    }

    __syncthreads();   // one full barrier: s_idx/s_prev visible to all

    // ---- initial x staging (t = 0): always from mem0 (prev == -1) ----
    float hold = 0.f;   // this gate thread's x_t (h_old), register-carried
    if (tid < 256) {
        hold = g_mem0[(size_t)s_idx[gc][0] * NE];
        xb[gc][ge] = f2bf(hold);
    }
    BARRIER();

    for (int t = 0; t < NS; ++t) {
        // ---- region-1a: issue async gather for x_{t+1} (no waits here) ----
        float vnext = 0.f;
        int pnext = -2;
        if (tid < 256 && t + 1 < NS) {
            pnext = s_prev[gc][t + 1];
            const int nidx = s_idx[gc][t + 1];
            if (pnext < 0)           vnext = g_mem0[(size_t)nidx * NE];
            else if (pnext <= t - 8) vnext = g_out[(size_t)pnext * NE];
            // pnext in [t-7, t]: resolved from register / LDS hh in region-2
        }

        // ---- region-1b: y = W_stack @ [ue, ie] via MFMA ----
        // B columns 2..15 are don't-care (D[:,c] depends only on B[:,c]),
        // so all lanes read valid xb rows 0/1 — no zeroing, no divergence.
        const int bc = col & 1;
        bf16x8 bfrag[4];
#pragma unroll
        for (int kt = 0; kt < 4; ++kt)
            bfrag[kt] = *(const bf16x8*)&xb[bc][kt * 32 + kgrp * 8];

        f32x4 acc[9];
#pragma unroll
        for (int m9 = 0; m9 < 9; ++m9) acc[m9] = (f32x4){0.f, 0.f, 0.f, 0.f};
        // kt-outer: 9 independent chains, dep distance 9 -> fully pipelined
#pragma unroll
        for (int kt = 0; kt < 4; ++kt)
#pragma unroll
            for (int m9 = 0; m9 < 9; ++m9)
                acc[m9] = __builtin_amdgcn_mfma_f32_16x16x32_bf16(
                    wfrag[m9][kt], bfrag[kt], acc[m9], 0, 0, 0);

        if (col < 2) {   // D layout: col = lane&15, row = (lane>>4)*4 + reg
#pragma unroll
            for (int m9 = 0; m9 < 9; ++m9) {
                const int row = wave * 144 + m9 * 16 + kgrp * 4;
                *(f32x4*)&y[col][row] = acc[m9];
            }
        }
        BARRIER();   // barrier1: y visible; global ops stay in flight

        // ---- region-2: gates + output + stage next x ----
        if (tid < 256) {
            const int c1 = 1 - gc;
            // gi = A@x_self + B@x_other + b_ih ; gh = C@x_self + b_hh
            const float gir = y[gc][ge]        + y[c1][384 + ge] + bir;
            const float giz = y[gc][128 + ge]  + y[c1][512 + ge] + biz;
            const float gin = y[gc][256 + ge]  + y[c1][640 + ge] + bin;
            const float ghr = y[gc][768 + ge]  + bhr;
            const float ghz = y[gc][896 + ge]  + bhz;
            const float ghn = y[gc][1024 + ge] + bhn;
            const float r = 1.f / (1.f + __expf(-(gir + ghr)));
            const float z = 1.f / (1.f + __expf(-(giz + ghz)));
            const float pre = gin + r * ghn;
            const float n = 2.f / (1.f + __expf(-2.f * pre)) - 1.f;   // tanh
            const float h = (1.f - z) * n + z * hold;
            g_out[(size_t)t * NE] = h;       // async store (undrained)
            hh[gc][t & 7][ge] = h;           // LDS history (barrier-ordered)
            if (t + 1 < NS) {
                float nx;
                if (pnext == t)                        nx = h;
                else if (pnext >= 0 && pnext >= t - 7) nx = hh[gc][pnext & 7][ge];
                else                                   nx = vnext;
                hold = nx;
                xb[gc][ge] = f2bf(nx);
            }
        }
        BARRIER();   // barrier2: xb visible for next step's MFMA
    }
}

extern "C" void kernel_launch(void* const* d_in, const int* in_sizes, int n_in,
                              void* d_out, int out_size, void* d_ws, size_t ws_size,
                              hipStream_t stream) {
    const int*   users = (const int*)d_in[0];
    const int*   items = (const int*)d_in[1];
    const float* umem0 = (const float*)d_in[2];
    const float* imem0 = (const float*)d_in[3];
    const float* w_ih  = (const float*)d_in[4];
    const float* w_hh  = (const float*)d_in[5];
    const float* b_ih  = (const float*)d_in[6];
    const float* b_hh  = (const float*)d_in[7];

    float* uout = (float*)d_out;
    float* iout = uout + (size_t)NB * NS * NE;

    int* prevU = (int*)d_ws;
    int* prevI = prevU + NB * NS;

    prev_kernel<<<dim3(NB, 2), dim3(NS), 0, stream>>>(users, items, prevU, prevI);
    limnet_main<<<dim3(NB), dim3(512), 0, stream>>>(
        users, items, umem0, imem0, w_ih, w_hh, b_ih, b_hh, prevU, prevI, uout, iout);
}

// Round 7
// 774.017 us; speedup vs baseline: 1.2351x; 1.0116x over previous
//
#include <hip/hip_runtime.h>

#define NB 32
#define NS 512
#define NE 128
#define NU 10000

typedef __attribute__((ext_vector_type(8))) short bf16x8;
typedef __attribute__((ext_vector_type(4))) float f32x4;

__device__ __forceinline__ unsigned short f2bf(float f) {
    unsigned int u = __float_as_uint(f);
    u += 0x7fff + ((u >> 16) & 1);   // round-to-nearest-even
    return (unsigned short)(u >> 16);
}

// LDS-only barrier: drain LDS ops (cross-wave write->read ordering), leave
// global loads/stores in flight across the barrier (no vmcnt drain).
// sched_barrier(0) stops the compiler from hoisting LDS reads above s_barrier.
#define BARRIER() do { \
    asm volatile("s_waitcnt lgkmcnt(0)" ::: "memory"); \
    __builtin_amdgcn_s_barrier(); \
    __builtin_amdgcn_sched_barrier(0); \
} while (0)

// Kernel 1: last-previous-occurrence tables for users and items.
__global__ void prev_kernel(const int* __restrict__ users, const int* __restrict__ items,
                            int* __restrict__ prevU, int* __restrict__ prevI) {
    const int b = blockIdx.x;
    const int which = blockIdx.y;
    const int t = threadIdx.x;
    const int* arr = (which ? items : users) + b * NS;
    __shared__ int sh[NS];
    sh[t] = arr[t];
    __syncthreads();
    const int idx = sh[t];
    int p = -1;
    for (int u = t - 1; u >= 0; --u) {
        if (sh[u] == idx) { p = u; break; }
    }
    (which ? prevI : prevU)[b * NS + t] = p;
}

// Kernel 2: one block per batch chain. 8 waves; W_stack (1152x128) in
// registers (AGPR-resident bf16 MFMA A-fragments). Per step T (4x unrolled,
// slot = one of 4 rotating gather registers, 4-step-deep pipeline):
//  region-1: y = W @ [ue, ie] via 36 MFMAs/wave (kt-outer, 9 live accs)
//  BARRIER (LDS-only drain)
//  region-2 (tid<256): gates; h -> g_out (undrained) + hh[T&15];
//            stage x_{T+1} from {h | hh window | slot}; then issue the
//            gather for step T+5's staging into slot (4 steps of slack).
//  BARRIER
__global__ __launch_bounds__(512, 1) void limnet_main(
    const int* __restrict__ users, const int* __restrict__ items,
    const float* __restrict__ umem0, const float* __restrict__ imem0,
    const float* __restrict__ w_ih, const float* __restrict__ w_hh,
    const float* __restrict__ b_ih, const float* __restrict__ b_hh,
    const int* __restrict__ prevU, const int* __restrict__ prevI,
    float* uout, float* iout)
{
    const int b = blockIdx.x;
    const int tid = threadIdx.x;
    const int lane = tid & 63;
    const int wave = tid >> 6;
    const int col = lane & 15;      // MFMA A row-in-tile / B-&-D column
    const int kgrp = lane >> 4;     // 0..3: which 8-wide k slice

    __shared__ __align__(16) float y[2][1152];           // y[col][row]
    __shared__ __align__(16) unsigned short xb[2][NE];   // bf16 x for MFMA
    __shared__ __align__(16) float hh[2][16][NE];        // h history (16 steps)
    __shared__ int s_idx[2][NS];
    __shared__ int s_prev[2][NS];

    // ---- stage idx/prev tables into LDS (one-time) ----
    for (int i = tid; i < NS; i += 512) {
        s_idx[0][i]  = users[b * NS + i];
        s_idx[1][i]  = items[b * NS + i];
        s_prev[0][i] = prevU[b * NS + i];
        s_prev[1][i] = prevI[b * NS + i];
    }

    // ---- one-time: load W_stack into registers as bf16 fragments ----
    // W_stack row R: R<384 -> w_ih[R, 0:128]; R<768 -> w_ih[R-384, 128:256];
    // else w_hh[R-768, :]. A-frag: lane holds A[row=col][k=kt*32+kgrp*8+j].
    bf16x8 wfrag[9][4];
#pragma unroll
    for (int m9 = 0; m9 < 9; ++m9) {
        const int row = wave * 144 + m9 * 16 + col;
#pragma unroll
        for (int kt = 0; kt < 4; ++kt) {
            const int k = kt * 32 + kgrp * 8;
            const float* src;
            if (row < 384)      src = w_ih + (size_t)row * 256 + k;
            else if (row < 768) src = w_ih + (size_t)(row - 384) * 256 + 128 + k;
            else                src = w_hh + (size_t)(row - 768) * 128 + k;
            const float4 f0 = *(const float4*)(src);
            const float4 f1 = *(const float4*)(src + 4);
            bf16x8 wv;
            wv[0] = (short)f2bf(f0.x); wv[1] = (short)f2bf(f0.y);
            wv[2] = (short)f2bf(f0.z); wv[3] = (short)f2bf(f0.w);
            wv[4] = (short)f2bf(f1.x); wv[5] = (short)f2bf(f1.y);
            wv[6] = (short)f2bf(f1.z); wv[7] = (short)f2bf(f1.w);
            wfrag[m9][kt] = wv;
        }
    }

    // gate-thread constants (threads 0..255: gc=cell (0=user,1=item), ge=elem)
    const int gc = (tid >> 7) & 1;
    const int ge = tid & 127;
    const float* g_mem0 = (gc ? imem0 : umem0) + (size_t)b * NU * NE + ge;
    float*       g_out  = (gc ? iout : uout) + (size_t)b * NS * NE + ge;

    float bir = 0.f, biz = 0.f, bin = 0.f, bhr = 0.f, bhz = 0.f, bhn = 0.f;
    if (tid < 256) {
        bir = b_ih[ge]; biz = b_ih[128 + ge]; bin = b_ih[256 + ge];
        bhr = b_hh[ge]; bhz = b_hh[128 + ge]; bhn = b_hh[256 + ge];
    }

    __syncthreads();   // one full barrier: s_idx/s_prev visible to all

    // ---- initial staging: x_0 (register+xb) and gather slots for x_1..x_4 ----
    float hold = 0.f;            // this gate thread's x_T (h_old)
    float sl0 = 0.f, sl1 = 0.f, sl2 = 0.f, sl3 = 0.f;   // 4-deep gather queue
    if (tid < 256) {
        hold = g_mem0[(size_t)s_idx[gc][0] * NE];
        xb[gc][ge] = f2bf(hold);
        // prologue gathers for targets 1..4: only the mem0 (p==-1) case can
        // need a global read; p>=0 at these depths is always hh/h-covered.
        if (s_prev[gc][1] < 0) sl0 = g_mem0[(size_t)s_idx[gc][1] * NE];
        if (s_prev[gc][2] < 0) sl1 = g_mem0[(size_t)s_idx[gc][2] * NE];
        if (s_prev[gc][3] < 0) sl2 = g_mem0[(size_t)s_idx[gc][3] * NE];
        if (s_prev[gc][4] < 0) sl3 = g_mem0[(size_t)s_idx[gc][4] * NE];
    }
    BARRIER();

    // Step body. Consume rule (staging x_{T+1}, p = prev[T+1]):
    //   p == T            -> h (this step's register)
    //   0 <= p >= T-15    -> hh[p & 15]   (window holds [T-15, T]; p&15==T&15
    //                        impossible here, that would be p==T-16)
    //   else (p==-1 or p<=T-16) -> slot (issued 4 steps ago; -1 -> mem0 row,
    //                        p<=T-16 -> g_out row, store retired >=12 steps)
    // Issue rule (at step T for target T+5, consumed at T+4): load slot iff
    //   pp == -1 (mem0) or pp < T-11 (== (T+4)-15, the hh-coverage edge).
#define STEP_BODY(T, slot)                                                     \
    {                                                                          \
        const int bc = col & 1;                                                \
        bf16x8 bfrag[4];                                                       \
        _Pragma("unroll")                                                      \
        for (int kt = 0; kt < 4; ++kt)                                         \
            bfrag[kt] = *(const bf16x8*)&xb[bc][kt * 32 + kgrp * 8];           \
        f32x4 acc[9];                                                          \
        _Pragma("unroll")                                                      \
        for (int m9 = 0; m9 < 9; ++m9) acc[m9] = (f32x4){0.f, 0.f, 0.f, 0.f};  \
        _Pragma("unroll")                                                      \
        for (int kt = 0; kt < 4; ++kt)                                         \
            _Pragma("unroll")                                                  \
            for (int m9 = 0; m9 < 9; ++m9)                                     \
                acc[m9] = __builtin_amdgcn_mfma_f32_16x16x32_bf16(             \
                    wfrag[m9][kt], bfrag[kt], acc[m9], 0, 0, 0);               \
        if (col < 2) {                                                         \
            _Pragma("unroll")                                                  \
            for (int m9 = 0; m9 < 9; ++m9) {                                   \
                const int row = wave * 144 + m9 * 16 + kgrp * 4;               \
                *(f32x4*)&y[col][row] = acc[m9];                               \
            }                                                                  \
        }                                                                      \
        BARRIER();                                                             \
        if (tid < 256) {                                                       \
            const int c1 = 1 - gc;                                             \
            const float gir = y[gc][ge]        + y[c1][384 + ge] + bir;        \
            const float giz = y[gc][128 + ge]  + y[c1][512 + ge] + biz;        \
            const float gin = y[gc][256 + ge]  + y[c1][640 + ge] + bin;        \
            const float ghr = y[gc][768 + ge]  + bhr;                          \
            const float ghz = y[gc][896 + ge]  + bhz;                          \
            const float ghn = y[gc][1024 + ge] + bhn;                          \
            const float r = 1.f / (1.f + __expf(-(gir + ghr)));                \
            const float z = 1.f / (1.f + __expf(-(giz + ghz)));                \
            const float pre = gin + r * ghn;                                   \
            const float n = 2.f / (1.f + __expf(-2.f * pre)) - 1.f;            \
            const float h = (1.f - z) * n + z * hold;                          \
            g_out[(size_t)(T) * NE] = h;                                       \
            hh[gc][(T) & 15][ge] = h;                                          \
            if ((T) + 1 < NS) {                                                \
                const int p = s_prev[gc][(T) + 1];                             \
                float nx;                                                      \
                if (p == (T))                    nx = h;                       \
                else if (p >= 0 && p >= (T) - 15) nx = hh[gc][p & 15][ge];     \
                else                              nx = slot;                   \
                hold = nx;                                                     \
                xb[gc][ge] = f2bf(nx);                                         \
            }                                                                  \
            if ((T) + 5 < NS) {                                                \
                const int pp = s_prev[gc][(T) + 5];                            \
                if (pp < 0)                                                    \
                    slot = g_mem0[(size_t)s_idx[gc][(T) + 5] * NE];            \
                else if (pp < (T) - 11)                                        \
                    slot = g_out[(size_t)pp * NE];                             \
            }                                                                  \
        }                                                                      \
        BARRIER();                                                             \
    }

    for (int t = 0; t < NS; t += 4) {
        STEP_BODY(t + 0, sl0)
        STEP_BODY(t + 1, sl1)
        STEP_BODY(t + 2, sl2)
        STEP_BODY(t + 3, sl3)
    }
#undef STEP_BODY
}

extern "C" void kernel_launch(void* const* d_in, const int* in_sizes, int n_in,
                              void* d_out, int out_size, void* d_ws, size_t ws_size,
                              hipStream_t stream) {
    const int*   users = (const int*)d_in[0];
    const int*   items = (const int*)d_in[1];
    const float* umem0 = (const float*)d_in[2];
    const float* imem0 = (const float*)d_in[3];
    const float* w_ih  = (const float*)d_in[4];
    const float* w_hh  = (const float*)d_in[5];
    const float* b_ih  = (const float*)d_in[6];
    const float* b_hh  = (const float*)d_in[7];

    float* uout = (float*)d_out;
    float* iout = uout + (size_t)NB * NS * NE;

    int* prevU = (int*)d_ws;
    int* prevI = prevU + NB * NS;

    prev_kernel<<<dim3(NB, 2), dim3(NS), 0, stream>>>(users, items, prevU, prevI);
    limnet_main<<<dim3(NB), dim3(512), 0, stream>>>(
        users, items, umem0, imem0, w_ih, w_hh, b_ih, b_hh, prevU, prevI, uout, iout);
}

// Round 9
// 239.814 us; speedup vs baseline: 3.9864x; 3.2276x over previous
//
#include <hip/hip_runtime.h>

#define NB 32
#define NS 512
#define NE 128
#define NU 10000
#define RMAX 6

// ---- workspace layout (int units) ----
#define WS_PREVU 0                          // 16384
#define WS_PREVI 16384                      // 16384
#define WS_GCNT  32768                      // 16
#define WS_GLIST 32784                      // RMAX*16384
#define WS_SCNT  (WS_GLIST + RMAX*16384)    // 32
#define WS_SLIST (WS_SCNT + 32)             // 16384
#define WS_WBF   (WS_SLIST + 16384)         // 147456 ushorts = 73728 ints

typedef __attribute__((ext_vector_type(8))) short bf16x8;
typedef __attribute__((ext_vector_type(4))) float f32x4;

__device__ __forceinline__ unsigned short f2bf(float f) {
    unsigned int u = __float_as_uint(f);
    u += 0x7fff + ((u >> 16) & 1);   // round-to-nearest-even
    return (unsigned short)(u >> 16);
}

// ---- kernel 0: zero the atomic counters ----
__global__ void zero_kernel(int* ws) {
    const int t = threadIdx.x;
    if (t < 16) ws[WS_GCNT + t] = 0;
    if (t < 32) ws[WS_SCNT + t] = 0;
}

// ---- kernel 1: prev tables + DAG round assignment + round lists ----
// One block per b. round(t) = 1 + max(round(pU), round(pI)), -1 for no parent.
// Nodes with round < RMAX go to global per-round lists (two-level atomic
// reservation); round >= RMAX nodes go to a per-b t-ordered sweep list.
__global__ __launch_bounds__(512) void prep_kernel(
    const int* __restrict__ users, const int* __restrict__ items, int* ws)
{
    const int b = blockIdx.x, tid = threadIdx.x;
    __shared__ int s_u[NS], s_i[NS], s_pU[NS], s_pI[NS], s_slot[NS];
    __shared__ unsigned char s_r[NS];
    __shared__ int lcnt[RMAX], lbase[RMAX];
    if (tid < RMAX) lcnt[tid] = 0;
    s_u[tid] = users[b * NS + tid];
    s_i[tid] = items[b * NS + tid];
    __syncthreads();
    {
        const int mu = s_u[tid], mi = s_i[tid];
        int pu = -1, pi = -1;
        for (int u = tid - 1; u >= 0; --u) if (s_u[u] == mu) { pu = u; break; }
        for (int u = tid - 1; u >= 0; --u) if (s_i[u] == mi) { pi = u; break; }
        s_pU[tid] = pu; s_pI[tid] = pi;
        ws[WS_PREVU + b * NS + tid] = pu;
        ws[WS_PREVI + b * NS + tid] = pi;
    }
    __syncthreads();
    if (tid == 0) {   // serial level assignment (parents have t' < t)
        int sc = 0;
        for (int t = 0; t < NS; ++t) {
            const int rU = s_pU[t] < 0 ? -1 : (int)s_r[s_pU[t]];
            const int rI = s_pI[t] < 0 ? -1 : (int)s_r[s_pI[t]];
            int r = 1 + (rU > rI ? rU : rI);
            if (r > 200) r = 200;
            s_r[t] = (unsigned char)r;
            if (r >= RMAX) { ws[WS_SLIST + b * NS + sc] = t; ++sc; }
        }
        ws[WS_SCNT + b] = sc;
    }
    __syncthreads();
    {
        const int r = s_r[tid];
        if (r < RMAX) s_slot[tid] = atomicAdd(&lcnt[r], 1);
    }
    __syncthreads();
    if (tid < RMAX) lbase[tid] = atomicAdd(&ws[WS_GCNT + tid], lcnt[tid]);
    __syncthreads();
    {
        const int r = s_r[tid];
        if (r < RMAX)
            ws[WS_GLIST + r * 16384 + lbase[r] + s_slot[tid]] = b * NS + tid;
    }
}

// ---- kernel 2: W_stack (1152x128) -> bf16 in ws ----
// row R: R<384 -> w_ih[R,0:128]; R<768 -> w_ih[R-384,128:256]; else w_hh[R-768]
__global__ void convw_kernel(const float* __restrict__ w_ih,
                             const float* __restrict__ w_hh, int* ws) {
    const int idx = blockIdx.x * 512 + threadIdx.x;
    if (idx >= 1152 * 128) return;
    const int r = idx >> 7, k = idx & 127;
    float v;
    if (r < 384)      v = w_ih[r * 256 + k];
    else if (r < 768) v = w_ih[(r - 384) * 256 + 128 + k];
    else              v = w_hh[(r - 768) * 128 + k];
    ((unsigned short*)(ws + WS_WBF))[idx] = f2bf(v);
}

// ---- kernel 3: per-round batched GEMM+gates ----
// 256 persistent blocks, W in registers (AGPR), chunks of 8 nodes = 16 MFMA
// B-columns (all useful). Per chunk: gather x (mem0 or earlier-round h) ->
// MFMA y[16][1152] -> gates -> scatter h to uout/iout.
__global__ __launch_bounds__(512, 1) void round_gemm(
    const int* __restrict__ users, const int* __restrict__ items,
    const float* __restrict__ umem0, const float* __restrict__ imem0,
    const float* __restrict__ b_ih, const float* __restrict__ b_hh,
    const int* __restrict__ ws, float* uout, float* iout, int r)
{
    const int count = ws[WS_GCNT + r];
    const int nch = (count + 7) >> 3;
    if ((int)blockIdx.x >= nch) return;
    const int tid = threadIdx.x;
    const int lane = tid & 63, wave = tid >> 6;
    const int col = lane & 15, kgrp = lane >> 4;

    __shared__ __align__(16) float yl[16 * 1156];          // 73.98 KB
    __shared__ __align__(16) float xf[16 * 132];           // f32 x (hold)
    __shared__ __align__(16) unsigned short xb[16 * 136];  // bf16 x
    __shared__ float b6[768];
    __shared__ unsigned long long srcs[16];
    __shared__ unsigned long long hdst[16];

    for (int i = tid; i < 768; i += 512)
        b6[i] = i < 384 ? b_ih[i] : b_hh[i - 384];

    // W fragments: lane holds A[row=col][k=kt*32+kgrp*8+j] per (m9,kt) tile
    const unsigned short* wbf = (const unsigned short*)(ws + WS_WBF);
    bf16x8 wfrag[9][4];
#pragma unroll
    for (int m9 = 0; m9 < 9; ++m9) {
        const int row = wave * 144 + m9 * 16 + col;
#pragma unroll
        for (int kt = 0; kt < 4; ++kt)
            wfrag[m9][kt] = *(const bf16x8*)&wbf[row * 128 + kt * 32 + kgrp * 8];
    }

    const int* glist = ws + WS_GLIST + r * 16384;
    const int* prevU = ws + WS_PREVU;
    const int* prevI = ws + WS_PREVI;

    for (int ch = blockIdx.x; ch < nch; ch += gridDim.x) {
        // meta: col c -> node (c>>1), cell (c&1); src row + h-dst pointers
        if (tid < 16) {
            const int j = ch * 8 + (tid >> 1);
            unsigned long long sp = 0, hd = 0;
            if (j < count) {
                const int node = glist[j];
                const int bb = node >> 9;            // node = b*NS + t
                const int cell = tid & 1;
                const int p = cell ? prevI[node] : prevU[node];
                const float* s;
                if (p < 0) {
                    const int ix = cell ? items[node] : users[node];
                    s = (cell ? imem0 : umem0) + ((size_t)bb * NU + ix) * NE;
                } else {
                    s = (cell ? iout : uout) + ((size_t)(bb * NS + p)) * NE;
                }
                sp = (unsigned long long)s;
                hd = (unsigned long long)((cell ? iout : uout) + (size_t)node * NE);
            }
            srcs[tid] = sp; hdst[tid] = hd;
        }
        __syncthreads();
        // gather: 32 threads per col, float4 each -> xf (f32) + xb (bf16)
        {
            const int c = tid >> 5, e4 = (tid & 31) * 4;
            const float* s = (const float*)srcs[c];
            if (s) {
                const float4 v = *(const float4*)(s + e4);
                *(float4*)&xf[c * 132 + e4] = v;
                ushort4 w4;
                w4.x = f2bf(v.x); w4.y = f2bf(v.y);
                w4.z = f2bf(v.z); w4.w = f2bf(v.w);
                *(ushort4*)&xb[c * 136 + e4] = w4;
            }
        }
        __syncthreads();
        // MFMA: y[col 16][1152] = W @ X; kt-outer, 9 independent acc chains
        {
            bf16x8 bfrag[4];
#pragma unroll
            for (int kt = 0; kt < 4; ++kt)
                bfrag[kt] = *(const bf16x8*)&xb[col * 136 + kt * 32 + kgrp * 8];
            f32x4 acc[9];
#pragma unroll
            for (int m9 = 0; m9 < 9; ++m9) acc[m9] = (f32x4){0.f, 0.f, 0.f, 0.f};
#pragma unroll
            for (int kt = 0; kt < 4; ++kt)
#pragma unroll
                for (int m9 = 0; m9 < 9; ++m9)
                    acc[m9] = __builtin_amdgcn_mfma_f32_16x16x32_bf16(
                        wfrag[m9][kt], bfrag[kt], acc[m9], 0, 0, 0);
#pragma unroll
            for (int m9 = 0; m9 < 9; ++m9)   // D: col=lane&15, row=kgrp*4+reg
                *(f32x4*)&yl[col * 1156 + wave * 144 + m9 * 16 + kgrp * 4] = acc[m9];
        }
        __syncthreads();
        // gates: 2048 (col, elem) items over 512 threads
#pragma unroll
        for (int it = 0; it < 4; ++it) {
            const int idx = tid + it * 512;
            const int c = idx >> 7, e = idx & 127;
            float* hb = (float*)hdst[c];
            if (hb) {
                const float* ys = &yl[c * 1156];
                const float* yo = &yl[(c ^ 1) * 1156];
                const float gir = ys[e]        + yo[384 + e] + b6[e];
                const float giz = ys[128 + e]  + yo[512 + e] + b6[128 + e];
                const float gin = ys[256 + e]  + yo[640 + e] + b6[256 + e];
                const float ghr = ys[768 + e]  + b6[384 + e];
                const float ghz = ys[896 + e]  + b6[512 + e];
                const float ghn = ys[1024 + e] + b6[640 + e];
                const float rr = 1.f / (1.f + __expf(-(gir + ghr)));
                const float z  = 1.f / (1.f + __expf(-(giz + ghz)));
                const float pre = gin + rr * ghn;
                const float n = 2.f / (1.f + __expf(-2.f * pre)) - 1.f;  // tanh
                hb[e] = (1.f - z) * n + z * xf[c * 132 + e];
            }
        }
        __syncthreads();
    }
}

// ---- kernel 4: sequential sweeper for depth >= RMAX (normally no work) ----
__global__ __launch_bounds__(256) void sweep_kernel(
    const int* __restrict__ users, const int* __restrict__ items,
    const float* __restrict__ umem0, const float* __restrict__ imem0,
    const float* __restrict__ w_ih, const float* __restrict__ w_hh,
    const float* __restrict__ b_ih, const float* __restrict__ b_hh,
    const int* __restrict__ ws, float* uout, float* iout)
{
    const int b = blockIdx.x;
    const int n = ws[WS_SCNT + b];
    if (n == 0) return;
    const int tid = threadIdx.x;
    const int cell = tid >> 7, e = tid & 127;
    __shared__ float xs[2][NE];
    const int* prevU = ws + WS_PREVU;
    const int* prevI = ws + WS_PREVI;
    for (int k = 0; k < n; ++k) {
        const int t = ws[WS_SLIST + b * NS + k];
        const int node = b * NS + t;
        const int p = cell ? prevI[node] : prevU[node];
        float v;
        if (p < 0) {
            const int ix = cell ? items[node] : users[node];
            v = (cell ? imem0 : umem0)[((size_t)b * NU + ix) * NE + e];
        } else {
            const volatile float* src =
                (cell ? iout : uout) + ((size_t)(b * NS + p)) * NE;
            v = src[e];
        }
        xs[cell][e] = v;
        __syncthreads();
        {
            const float* self = xs[cell];
            const float* oth  = xs[cell ^ 1];
            float gir = b_ih[e], giz = b_ih[128 + e], gin = b_ih[256 + e];
            float ghr = b_hh[e], ghz = b_hh[128 + e], ghn = b_hh[256 + e];
            for (int kk = 0; kk < NE; ++kk) {
                const float su = self[kk], ot = oth[kk];
                gir += w_ih[(size_t)e * 256 + kk] * su
                     + w_ih[(size_t)e * 256 + 128 + kk] * ot;
                giz += w_ih[(size_t)(128 + e) * 256 + kk] * su
                     + w_ih[(size_t)(128 + e) * 256 + 128 + kk] * ot;
                gin += w_ih[(size_t)(256 + e) * 256 + kk] * su
                     + w_ih[(size_t)(256 + e) * 256 + 128 + kk] * ot;
                ghr += w_hh[(size_t)e * 128 + kk] * su;
                ghz += w_hh[(size_t)(128 + e) * 128 + kk] * su;
                ghn += w_hh[(size_t)(256 + e) * 128 + kk] * su;
            }
            const float rr = 1.f / (1.f + __expf(-(gir + ghr)));
            const float z  = 1.f / (1.f + __expf(-(giz + ghz)));
            const float pre = gin + rr * ghn;
            const float nn = 2.f / (1.f + __expf(-2.f * pre)) - 1.f;
            (cell ? iout : uout)[(size_t)node * NE + e] =
                (1.f - z) * nn + z * self[e];
        }
        __threadfence();
        __syncthreads();
    }
}

extern "C" void kernel_launch(void* const* d_in, const int* in_sizes, int n_in,
                              void* d_out, int out_size, void* d_ws, size_t ws_size,
                              hipStream_t stream) {
    const int*   users = (const int*)d_in[0];
    const int*   items = (const int*)d_in[1];
    const float* umem0 = (const float*)d_in[2];
    const float* imem0 = (const float*)d_in[3];
    const float* w_ih  = (const float*)d_in[4];
    const float* w_hh  = (const float*)d_in[5];
    const float* b_ih  = (const float*)d_in[6];
    const float* b_hh  = (const float*)d_in[7];

    float* uout = (float*)d_out;
    float* iout = uout + (size_t)NB * NS * NE;
    int* ws = (int*)d_ws;

    zero_kernel<<<1, 64, 0, stream>>>(ws);
    prep_kernel<<<NB, 512, 0, stream>>>(users, items, ws);
    convw_kernel<<<288, 512, 0, stream>>>(w_ih, w_hh, ws);
    for (int r = 0; r < RMAX; ++r)
        round_gemm<<<256, 512, 0, stream>>>(users, items, umem0, imem0,
                                            b_ih, b_hh, ws, uout, iout, r);
    sweep_kernel<<<NB, 256, 0, stream>>>(users, items, umem0, imem0,
                                         w_ih, w_hh, b_ih, b_hh, ws, uout, iout);
}

// Round 10
// 122.507 us; speedup vs baseline: 7.8035x; 1.9575x over previous
//
#include <hip/hip_runtime.h>

#define NB 32
#define NS 512
#define NE 128
#define NU 10000

// ---- workspace layout (int units) ----
#define WS_PREVU 0                // 16384
#define WS_PREVI 16384            // 16384
#define WS_CNT0  32768            // 1: round-0 node count
#define WS_CNT1  32769            // 1: round-1 node count
#define WS_LCNT  32770            // 32: per-b late-list counts
#define WS_G0    32832            // 16384: round-0 node list
#define WS_G1    49216            // 16384: round-1 node list
#define WS_LATE  65600            // 16384: per-b late lists (t values)
#define WS_WBF   81984            // 147456 ushorts = 73728 ints (bf16 W)

typedef __attribute__((ext_vector_type(8))) short bf16x8;
typedef __attribute__((ext_vector_type(4))) float f32x4;

__device__ __forceinline__ unsigned short f2bf(float f) {
    unsigned int u = __float_as_uint(f);
    u += 0x7fff + ((u >> 16) & 1);   // round-to-nearest-even
    return (unsigned short)(u >> 16);
}

// ---- kernel 1: prev tables (64 blocks) + W->bf16 conversion (36 blocks) ----
// Blocks 0..63: (b = blk>>1, which = blk&1) backward prev-scan, 8-batched LDS
// reads to amortize the ~120cy dependent-read latency. Block 0 also zeros the
// two global counters. Blocks 64..99: convert W_stack rows to bf16 in ws.
__global__ __launch_bounds__(512) void prep1_kernel(
    const int* __restrict__ users, const int* __restrict__ items,
    const float* __restrict__ w_ih, const float* __restrict__ w_hh, int* ws)
{
    const int blk = blockIdx.x, tid = threadIdx.x;
    if (blk >= 64) {
        // convw: W_stack row R: R<384 -> w_ih[R,0:128]; R<768 ->
        // w_ih[R-384,128:256]; else w_hh[R-768,:]. 8 elems/thread, same row.
        const int base = (blk - 64) * 4096 + tid * 8;
        const int r = base >> 7, k = base & 127;
        const float* src;
        if (r < 384)      src = w_ih + (size_t)r * 256 + k;
        else if (r < 768) src = w_ih + (size_t)(r - 384) * 256 + 128 + k;
        else              src = w_hh + (size_t)(r - 768) * 128 + k;
        unsigned short* wbf = (unsigned short*)(ws + WS_WBF);
#pragma unroll
        for (int j = 0; j < 8; ++j) wbf[base + j] = f2bf(src[j]);
        return;
    }
    const int b = blk >> 1, which = blk & 1;
    if (blk == 0 && tid < 2) ws[WS_CNT0 + tid] = 0;
    __shared__ int s[NS];
    s[tid] = (which ? items : users)[b * NS + tid];
    __syncthreads();
    const int mid = s[tid];
    int p = -1;
    for (int u = tid - 1; u >= 0 && p < 0; u -= 8) {
        int vals[8];
#pragma unroll
        for (int j = 0; j < 8; ++j) {
            const int uu = u - j;
            vals[j] = (uu >= 0) ? s[uu] : -1;   // ids >= 0: no false match
        }
#pragma unroll
        for (int j = 0; j < 8; ++j)
            if (p < 0 && vals[j] == mid) p = u - j;   // largest u wins
    }
    ws[(which ? WS_PREVI : WS_PREVU) + b * NS + tid] = p;
}

// ---- kernel 2: parallel round classification + list build (32 blocks) ----
// State per node: 0 (no parents), 1 (parents all round-0), 2 (any deeper),
// 255 (unknown). Fixed-point relaxation, <= 16 passes, early exit. Monotonic
// lattice -> benign same-pass races. Unresolved (depth>16) stays 255 -> late.
// Lists: round-0 -> G0, round-1 -> G1 (two-level atomic reservation);
// r>=2 or 255 -> per-b late list in t-order (topological within b).
__global__ __launch_bounds__(512) void prep2_kernel(int* ws)
{
    const int b = blockIdx.x, tid = threadIdx.x;
    __shared__ short s_pU[NS], s_pI[NS];
    __shared__ unsigned char s_r[NS];
    __shared__ int c0, c1, base0, base1, s_chg;
    const int pU = ws[WS_PREVU + (b << 9) + tid];
    const int pI = ws[WS_PREVI + (b << 9) + tid];
    s_pU[tid] = (short)pU;
    s_pI[tid] = (short)pI;
    s_r[tid] = (pU < 0 && pI < 0) ? 0 : 255;
    if (tid == 0) { c0 = 0; c1 = 0; }
    __syncthreads();
    for (int pass = 0; pass < 16; ++pass) {
        if (tid == 0) s_chg = 0;
        __syncthreads();
        if (s_r[tid] == 255) {
            const int ru = pU < 0 ? -1 : (int)s_r[pU];
            const int ri = pI < 0 ? -1 : (int)s_r[pI];
            if (ru != 255 && ri != 255) {
                int rr = 1 + (ru > ri ? ru : ri);
                if (rr > 2) rr = 2;
                s_r[tid] = (unsigned char)rr;
                s_chg = 1;
            }
        }
        __syncthreads();
        if (!s_chg) break;
    }
    const int r = s_r[tid];
    int slot = -1;
    if (r == 0)      slot = atomicAdd(&c0, 1);
    else if (r == 1) slot = atomicAdd(&c1, 1);
    __syncthreads();
    if (tid == 0) {
        base0 = atomicAdd(&ws[WS_CNT0], c0);
        base1 = atomicAdd(&ws[WS_CNT1], c1);
    }
    __syncthreads();
    const int node = (b << 9) + tid;
    if (r == 0)      ws[WS_G0 + base0 + slot] = node;
    else if (r == 1) ws[WS_G1 + base1 + slot] = node;
    if (tid == 0) {   // late list, t-order (512 independent byte reads)
        int n = 0;
        for (int t = 0; t < NS; ++t)
            if (s_r[t] >= 2) { ws[WS_LATE + (b << 9) + n] = t; ++n; }
        ws[WS_LCNT + b] = n;
    }
}

// ---- kernel 3: batched GEMM+gates for one round list ----
// 256 blocks, W in registers, chunks of 8 nodes = 16 MFMA B-columns.
__global__ __launch_bounds__(512, 1) void round_gemm(
    const int* __restrict__ users, const int* __restrict__ items,
    const float* __restrict__ umem0, const float* __restrict__ imem0,
    const float* __restrict__ b_ih, const float* __restrict__ b_hh,
    const int* __restrict__ ws, float* uout, float* iout,
    int cnt_off, int list_off)
{
    const int count = ws[cnt_off];
    const int nch = (count + 7) >> 3;
    if ((int)blockIdx.x >= nch) return;
    const int tid = threadIdx.x;
    const int lane = tid & 63, wave = tid >> 6;
    const int col = lane & 15, kgrp = lane >> 4;

    __shared__ __align__(16) float yl[16 * 1156];
    __shared__ __align__(16) float xf[16 * 132];
    __shared__ __align__(16) unsigned short xb[16 * 136];
    __shared__ float b6[768];
    __shared__ unsigned long long srcs[16];
    __shared__ unsigned long long hdst[16];

    for (int i = tid; i < 768; i += 512)
        b6[i] = i < 384 ? b_ih[i] : b_hh[i - 384];

    const unsigned short* wbf = (const unsigned short*)(ws + WS_WBF);
    bf16x8 wfrag[9][4];
#pragma unroll
    for (int m9 = 0; m9 < 9; ++m9) {
        const int row = wave * 144 + m9 * 16 + col;
#pragma unroll
        for (int kt = 0; kt < 4; ++kt)
            wfrag[m9][kt] = *(const bf16x8*)&wbf[row * 128 + kt * 32 + kgrp * 8];
    }

    const int* glist = ws + list_off;
    const int* prevU = ws + WS_PREVU;
    const int* prevI = ws + WS_PREVI;

    for (int ch = blockIdx.x; ch < nch; ch += gridDim.x) {
        if (tid < 16) {
            const int j = ch * 8 + (tid >> 1);
            unsigned long long sp = 0, hd = 0;
            if (j < count) {
                const int node = glist[j];
                const int bb = node >> 9;
                const int cell = tid & 1;
                const int p = cell ? prevI[node] : prevU[node];
                const float* s;
                if (p < 0) {
                    const int ix = cell ? items[node] : users[node];
                    s = (cell ? imem0 : umem0) + ((size_t)bb * NU + ix) * NE;
                } else {
                    s = (cell ? iout : uout) + ((size_t)((bb << 9) + p)) * NE;
                }
                sp = (unsigned long long)s;
                hd = (unsigned long long)((cell ? iout : uout) + (size_t)node * NE);
            }
            srcs[tid] = sp; hdst[tid] = hd;
        }
        __syncthreads();
        {
            const int c = tid >> 5, e4 = (tid & 31) * 4;
            const float* s = (const float*)srcs[c];
            if (s) {
                const float4 v = *(const float4*)(s + e4);
                *(float4*)&xf[c * 132 + e4] = v;
                ushort4 w4;
                w4.x = f2bf(v.x); w4.y = f2bf(v.y);
                w4.z = f2bf(v.z); w4.w = f2bf(v.w);
                *(ushort4*)&xb[c * 136 + e4] = w4;
            }
        }
        __syncthreads();
        {
            bf16x8 bfrag[4];
#pragma unroll
            for (int kt = 0; kt < 4; ++kt)
                bfrag[kt] = *(const bf16x8*)&xb[col * 136 + kt * 32 + kgrp * 8];
            f32x4 acc[9];
#pragma unroll
            for (int m9 = 0; m9 < 9; ++m9) acc[m9] = (f32x4){0.f, 0.f, 0.f, 0.f};
#pragma unroll
            for (int kt = 0; kt < 4; ++kt)
#pragma unroll
                for (int m9 = 0; m9 < 9; ++m9)
                    acc[m9] = __builtin_amdgcn_mfma_f32_16x16x32_bf16(
                        wfrag[m9][kt], bfrag[kt], acc[m9], 0, 0, 0);
#pragma unroll
            for (int m9 = 0; m9 < 9; ++m9)
                *(f32x4*)&yl[col * 1156 + wave * 144 + m9 * 16 + kgrp * 4] = acc[m9];
        }
        __syncthreads();
#pragma unroll
        for (int it = 0; it < 4; ++it) {
            const int idx = tid + it * 512;
            const int c = idx >> 7, e = idx & 127;
            float* hb = (float*)hdst[c];
            if (hb) {
                const float* ys = &yl[c * 1156];
                const float* yo = &yl[(c ^ 1) * 1156];
                const float gir = ys[e]        + yo[384 + e] + b6[e];
                const float giz = ys[128 + e]  + yo[512 + e] + b6[128 + e];
                const float gin = ys[256 + e]  + yo[640 + e] + b6[256 + e];
                const float ghr = ys[768 + e]  + b6[384 + e];
                const float ghz = ys[896 + e]  + b6[512 + e];
                const float ghn = ys[1024 + e] + b6[640 + e];
                const float rr = 1.f / (1.f + __expf(-(gir + ghr)));
                const float z  = 1.f / (1.f + __expf(-(giz + ghz)));
                const float pre = gin + rr * ghn;
                const float n = 2.f / (1.f + __expf(-2.f * pre)) - 1.f;  // tanh
                hb[e] = (1.f - z) * n + z * xf[c * 132 + e];
            }
        }
        __syncthreads();
    }
}

// ---- kernel 4: late nodes (round >= 2), block b in t-order, MFMA path ----
// Parents are round-0/1 (visible via kernel boundary) or earlier late nodes
// of the same block (visible via threadfence+syncthreads, same CU).
__global__ __launch_bounds__(512, 1) void cleanup_kernel(
    const int* __restrict__ users, const int* __restrict__ items,
    const float* __restrict__ umem0, const float* __restrict__ imem0,
    const float* __restrict__ b_ih, const float* __restrict__ b_hh,
    const int* __restrict__ ws, float* uout, float* iout)
{
    const int b = blockIdx.x;
    const int n = ws[WS_LCNT + b];
    if (n == 0) return;
    const int tid = threadIdx.x;
    const int lane = tid & 63, wave = tid >> 6;
    const int col = lane & 15, kgrp = lane >> 4;

    __shared__ __align__(16) float yl[2][1156];
    __shared__ __align__(16) float xf[2][132];
    __shared__ __align__(16) unsigned short xb[2][136];
    __shared__ float b6[768];
    __shared__ const float* srcs[2];

    for (int i = tid; i < 768; i += 512)
        b6[i] = i < 384 ? b_ih[i] : b_hh[i - 384];

    const unsigned short* wbf = (const unsigned short*)(ws + WS_WBF);
    bf16x8 wfrag[9][4];
#pragma unroll
    for (int m9 = 0; m9 < 9; ++m9) {
        const int row = wave * 144 + m9 * 16 + col;
#pragma unroll
        for (int kt = 0; kt < 4; ++kt)
            wfrag[m9][kt] = *(const bf16x8*)&wbf[row * 128 + kt * 32 + kgrp * 8];
    }

    const int* prevU = ws + WS_PREVU;
    const int* prevI = ws + WS_PREVI;

    for (int k = 0; k < n; ++k) {
        const int t = ws[WS_LATE + (b << 9) + k];
        const int node = (b << 9) + t;
        if (tid < 2) {
            const int cell = tid;
            const int p = cell ? prevI[node] : prevU[node];
            const float* sp;
            if (p < 0) {
                const int ix = cell ? items[node] : users[node];
                sp = (cell ? imem0 : umem0) + ((size_t)b * NU + ix) * NE;
            } else {
                sp = (cell ? iout : uout) + ((size_t)((b << 9) + p)) * NE;
            }
            srcs[cell] = sp;
        }
        __syncthreads();
        if (tid < 64) {
            const int c = tid >> 5, e4 = (tid & 31) * 4;
            const float4 v = *(const float4*)(srcs[c] + e4);
            *(float4*)&xf[c][e4] = v;
            ushort4 w4;
            w4.x = f2bf(v.x); w4.y = f2bf(v.y);
            w4.z = f2bf(v.z); w4.w = f2bf(v.w);
            *(ushort4*)&xb[c][e4] = w4;
        }
        __syncthreads();
        {
            const int bc = col & 1;
            bf16x8 bfrag[4];
#pragma unroll
            for (int kt = 0; kt < 4; ++kt)
                bfrag[kt] = *(const bf16x8*)&xb[bc][kt * 32 + kgrp * 8];
            f32x4 acc[9];
#pragma unroll
            for (int m9 = 0; m9 < 9; ++m9) acc[m9] = (f32x4){0.f, 0.f, 0.f, 0.f};
#pragma unroll
            for (int kt = 0; kt < 4; ++kt)
#pragma unroll
                for (int m9 = 0; m9 < 9; ++m9)
                    acc[m9] = __builtin_amdgcn_mfma_f32_16x16x32_bf16(
                        wfrag[m9][kt], bfrag[kt], acc[m9], 0, 0, 0);
            if (col < 2) {
#pragma unroll
                for (int m9 = 0; m9 < 9; ++m9)
                    *(f32x4*)&yl[col][wave * 144 + m9 * 16 + kgrp * 4] = acc[m9];
            }
        }
        __syncthreads();
        if (tid < 256) {
            const int c = tid >> 7, e = tid & 127;
            const float* ys = yl[c];
            const float* yo = yl[c ^ 1];
            const float gir = ys[e]        + yo[384 + e] + b6[e];
            const float giz = ys[128 + e]  + yo[512 + e] + b6[128 + e];
            const float gin = ys[256 + e]  + yo[640 + e] + b6[256 + e];
            const float ghr = ys[768 + e]  + b6[384 + e];
            const float ghz = ys[896 + e]  + b6[512 + e];
            const float ghn = ys[1024 + e] + b6[640 + e];
            const float rr = 1.f / (1.f + __expf(-(gir + ghr)));
            const float z  = 1.f / (1.f + __expf(-(giz + ghz)));
            const float pre = gin + rr * ghn;
            const float nn = 2.f / (1.f + __expf(-2.f * pre) ) - 1.f;
            (c ? iout : uout)[(size_t)node * NE + e] =
                (1.f - z) * nn + z * xf[c][e];
        }
        __threadfence();
        __syncthreads();
    }
}

extern "C" void kernel_launch(void* const* d_in, const int* in_sizes, int n_in,
                              void* d_out, int out_size, void* d_ws, size_t ws_size,
                              hipStream_t stream) {
    const int*   users = (const int*)d_in[0];
    const int*   items = (const int*)d_in[1];
    const float* umem0 = (const float*)d_in[2];
    const float* imem0 = (const float*)d_in[3];
    const float* w_ih  = (const float*)d_in[4];
    const float* w_hh  = (const float*)d_in[5];
    const float* b_ih  = (const float*)d_in[6];
    const float* b_hh  = (const float*)d_in[7];

    float* uout = (float*)d_out;
    float* iout = uout + (size_t)NB * NS * NE;
    int* ws = (int*)d_ws;

    prep1_kernel<<<100, 512, 0, stream>>>(users, items, w_ih, w_hh, ws);
    prep2_kernel<<<NB, 512, 0, stream>>>(ws);
    round_gemm<<<256, 512, 0, stream>>>(users, items, umem0, imem0,
                                        b_ih, b_hh, ws, uout, iout,
                                        WS_CNT0, WS_G0);
    round_gemm<<<256, 512, 0, stream>>>(users, items, umem0, imem0,
                                        b_ih, b_hh, ws, uout, iout,
                                        WS_CNT1, WS_G1);
    cleanup_kernel<<<NB, 512, 0, stream>>>(users, items, umem0, imem0,
                                           b_ih, b_hh, ws, uout, iout);
}